// Round 6
// baseline (374.180 us; speedup 1.0000x reference)
//
#include <hip/hip_runtime.h>
#include <stdint.h>

#define EMBED  768
#define HEADS  12
#define HDIM   64
#define HIDDEN 3072
#define BSZ    2
#define SEQ    2048
#define NTOK   4096
#define QKVN   2304

typedef short short8 __attribute__((ext_vector_type(8)));
typedef float f32x4 __attribute__((ext_vector_type(4)));
typedef float float4v __attribute__((ext_vector_type(4)));
typedef unsigned short ushort4v __attribute__((ext_vector_type(4)));

__device__ __forceinline__ unsigned short f2bf(float f) {
    uint32_t x = __builtin_bit_cast(uint32_t, f);
    x = x + 0x7fffu + ((x >> 16) & 1u);   // RNE
    return (unsigned short)(x >> 16);
}
__device__ __forceinline__ void load16(const void* g, void* l) {
    __builtin_amdgcn_global_load_lds((const __attribute__((address_space(1))) void*)g,
                                     (__attribute__((address_space(3))) void*)l, 16, 0, 0);
}

// ---------------- fp32 -> bf16 convert, all 4 weights in one launch ----------------
__global__ __launch_bounds__(256) void cvt4_k(const float* __restrict__ s0, unsigned short* __restrict__ o0, int n0,
                                              const float* __restrict__ s1, unsigned short* __restrict__ o1, int n1,
                                              const float* __restrict__ s2, unsigned short* __restrict__ o2, int n2,
                                              const float* __restrict__ s3, unsigned short* __restrict__ o3, int n3) {
    int i = blockIdx.x * blockDim.x + threadIdx.x;
    const int stride = gridDim.x * blockDim.x;
    const int tot = n0 + n1 + n2 + n3;   // float4 units
    for (; i < tot; i += stride) {
        const float* s; unsigned short* o; int j = i;
        if (j < n0) { s = s0; o = o0; }
        else if ((j -= n0) < n1) { s = s1; o = o1; }
        else if ((j -= n1) < n2) { s = s2; o = o2; }
        else { j -= n2; s = s3; o = o3; }
        float4v v = ((const float4v*)s)[j];
        ushort4v u;
#pragma unroll
        for (int t = 0; t < 4; t++) u[t] = f2bf(v[t]);
        ((ushort4v*)o)[j] = u;
    }
}

// ---------------- LayerNorm (fp32 in, bf16 out) ----------------
__global__ __launch_bounds__(256) void ln_k(const float* __restrict__ x,
                                            const float* __restrict__ g,
                                            const float* __restrict__ b,
                                            unsigned short* __restrict__ out) {
    const int row = blockIdx.x;
    const int t = threadIdx.x;
    const float* xr = x + (size_t)row * EMBED;
    float v0 = xr[t], v1 = xr[t + 256], v2 = xr[t + 512];
    float s = v0 + v1 + v2;
    float s2 = v0 * v0 + v1 * v1 + v2 * v2;
#pragma unroll
    for (int m = 1; m < 64; m <<= 1) { s += __shfl_xor(s, m); s2 += __shfl_xor(s2, m); }
    __shared__ float red[8];
    const int w = t >> 6;
    if ((t & 63) == 0) { red[w] = s; red[4 + w] = s2; }
    __syncthreads();
    s = red[0] + red[1] + red[2] + red[3];
    s2 = red[4] + red[5] + red[6] + red[7];
    const float mu = s * (1.0f / EMBED);
    const float var = s2 * (1.0f / EMBED) - mu * mu;
    const float rs = rsqrtf(var + 1e-5f);
    unsigned short* orow = out + (size_t)row * EMBED;
    orow[t]       = f2bf((v0 - mu) * rs * g[t]       + b[t]);
    orow[t + 256] = f2bf((v1 - mu) * rs * g[t + 256] + b[t + 256]);
    orow[t + 512] = f2bf((v2 - mu) * rs * g[t + 512] + b[t + 512]);
}

// ---------------- GEMM: C[M,N] = A[M,K](bf16) * W[N,K]^T(bf16) + bias ----------------
// 3-buffer circular LDS pipeline with counted vmcnt (loads span barriers, never
// drained to 0 mid-loop), one s_barrier per 32-K step. Race-freedom: vmcnt(4)
// guarantees tile t landed; the barrier guarantees all waves consumed tile t-1
// (their ds_reads are lgkm-drained before the MFMAs that precede the barrier);
// stage(t+2) then overwrites buf(t-1).
// EPI: 0 = QKV (bf16 out + transposed-V side write), 1 = proj (+res, fp32 out),
//      2 = FC1 (GELU, bf16 out), 3 = FC2 (+res, fp32 out)
template <int EPI, int BM, int BN, int WM, int WN>
__global__ __launch_bounds__(WM * WN * 64, (WM * WN == 8) ? 2 : 3)
void gemm_bt(const unsigned short* __restrict__ A,
             const unsigned short* __restrict__ W,
             const float* __restrict__ bias,
             const float* __restrict__ res,
             void* __restrict__ outp,
             unsigned short* __restrict__ vt,
             int M, int N, int K) {
    constexpr int T = WM * WN * 64;            // threads
    constexpr int MI = BM / (WM * 16);         // 16-row fragments per wave (M)
    constexpr int NJ = BN / (WN * 16);         // 16-col fragments per wave (N)
    constexpr int BUFB = (BM + BN) * 64;       // bytes per K-step buffer (32k * 2B)
    constexpr int CH = T / 4;                  // rows per staging chunk
    __shared__ __align__(16) char smem[3 * BUFB];

    const int tid = threadIdx.x;
    const int w = tid >> 6, l = tid & 63;
    const int lr = l >> 4, lc = l & 15;
    const int nb = N / BN;

    // bijective XCD swizzle (gridDim.x % 8 == 0 for all our grids)
    int bid = blockIdx.x;
    bid = (bid & 7) * (gridDim.x >> 3) + (bid >> 3);
    const int bx = bid % nb, by = bid / nb;
    const int row0 = by * BM, col0 = bx * BN;
    const int wr = w / WN, wc = w % WN;
    const int srow = tid >> 2, skoff = (tid & 3) * 8;

    f32x4 acc[MI][NJ] = {};

    const unsigned short* Ag0 = A + (size_t)(row0 + srow) * K + skoff;
    const unsigned short* Ag1 = A + (size_t)(row0 + CH + srow) * K + skoff;
    const unsigned short* Wg0 = W + (size_t)(col0 + srow) * K + skoff;
    const unsigned short* Wg1 = W + (size_t)(col0 + CH + srow) * K + skoff;

    auto stage = [&](int buf, int k0) {
        char* base = smem + buf * BUFB;
        load16(Ag0 + k0, base + tid * 16);
        load16(Ag1 + k0, base + T * 16 + tid * 16);
        load16(Wg0 + k0, base + BM * 64 + tid * 16);
        load16(Wg1 + k0, base + BM * 64 + T * 16 + tid * 16);
    };
    auto compute = [&](int buf) {
        const unsigned short* Asb = (const unsigned short*)(smem + buf * BUFB);
        const unsigned short* Bsb = (const unsigned short*)(smem + buf * BUFB + BM * 64);
        short8 bfr[NJ];
#pragma unroll
        for (int j = 0; j < NJ; j++)
            bfr[j] = *(const short8*)&Bsb[(wc * NJ * 16 + j * 16 + lc) * 32 + 8 * lr];
#pragma unroll
        for (int i = 0; i < MI; i++) {
            short8 af = *(const short8*)&Asb[(wr * MI * 16 + i * 16 + lc) * 32 + 8 * lr];
#pragma unroll
            for (int j = 0; j < NJ; j++)
                acc[i][j] = __builtin_amdgcn_mfma_f32_16x16x32_bf16(af, bfr[j], acc[i][j], 0, 0, 0);
        }
    };

    const int nt = K / 32;
    stage(0, 0);
    stage(1, 32);
    int cur = 0;
    for (int t = 0; t < nt; ++t) {
        if (t + 1 < nt) asm volatile("s_waitcnt vmcnt(4)" ::: "memory");
        else            asm volatile("s_waitcnt vmcnt(0)" ::: "memory");
        __builtin_amdgcn_s_barrier();
        if (t + 2 < nt) {
            int nxt = cur + 2; if (nxt >= 3) nxt -= 3;
            stage(nxt, (t + 2) * 32);
        }
        compute(cur);
        cur = (cur == 2) ? 0 : cur + 1;
    }

    if (EPI == 0 || EPI == 2) {
        // ---- through-LDS coalesced bf16 epilogue (chunks of 64 rows/wave) ----
        __syncthreads();                       // stage bufs dead; reuse LDS
        unsigned short* ebuf = (unsigned short*)(smem + w * 9216);  // 64x72 shorts, wave-private
        unsigned short* qo = (unsigned short*)outp;
#pragma unroll
        for (int ch = 0; ch < MI; ch += 4) {
#pragma unroll
            for (int i2 = 0; i2 < 4; i2++) {
                const int i = ch + i2;
#pragma unroll
                for (int j = 0; j < NJ; j++) {
                    const int col = col0 + wc * NJ * 16 + j * 16 + lc;
                    const float bv = bias[col];
                    float v[4];
#pragma unroll
                    for (int r = 0; r < 4; r++) {
                        v[r] = acc[i][j][r] + bv;
                        if (EPI == 2) v[r] = 0.5f * v[r] * (1.0f + erff(v[r] * 0.70710678118f));
                    }
                    if (EPI == 0 && col >= 2 * EMBED) {   // V -> [bh][d][n]
                        const int r0 = row0 + wr * MI * 16 + i * 16 + 4 * lr;
                        const int hh = (col - 2 * EMBED) >> 6, d = col & 63;
                        const int bb = r0 >> 11, n0 = r0 & (SEQ - 1);
                        ushort4v pk;
#pragma unroll
                        for (int r = 0; r < 4; r++) pk[r] = f2bf(v[r]);
                        *(ushort4v*)&vt[((size_t)(bb * HEADS + hh) * HDIM + d) * SEQ + n0] = pk;
                    }
#pragma unroll
                    for (int r = 0; r < 4; r++)
                        ebuf[(i2 * 16 + 4 * lr + r) * 72 + j * 16 + lc] = f2bf(v[r]);
                }
            }
            const int growc = row0 + wr * MI * 16 + ch * 16;
            const int gcol = col0 + wc * NJ * 16;
            const int rl0 = l >> 3, c8 = (l & 7) * 8;
#pragma unroll
            for (int k = 0; k < 8; k++) {
                const int rl = k * 8 + rl0;
                short8 vv = *(const short8*)&ebuf[rl * 72 + c8];
                *(short8*)&qo[(size_t)(growc + rl) * N + gcol + c8] = vv;
            }
        }
    } else {
        float* fo = (float*)outp;
#pragma unroll
        for (int i = 0; i < MI; i++) {
            const int r0 = row0 + wr * MI * 16 + i * 16 + 4 * lr;
#pragma unroll
            for (int j = 0; j < NJ; j++) {
                const int col = col0 + wc * NJ * 16 + j * 16 + lc;
                const float bv = bias[col];
#pragma unroll
                for (int r = 0; r < 4; r++)
                    fo[(size_t)(r0 + r) * N + col] =
                        acc[i][j][r] + bv + res[(size_t)(r0 + r) * N + col];
            }
        }
    }
}

// ---------------- Flash attention ----------------
// grid (SEQ/64, BSZ*HEADS), 256 thr. Q tile 64 rows (16/wave), KV tiles 128.
__global__ __launch_bounds__(256) void attn_k(const unsigned short* __restrict__ qkv,
                                              const unsigned short* __restrict__ vt,
                                              unsigned short* __restrict__ o_out) {
    __shared__ __align__(16) unsigned short Ks[128 * 64];    // [kv][d]  XOR-swizzled
    __shared__ __align__(16) unsigned short Vs[64 * 128];    // [d][kv]  XOR-swizzled
    __shared__ __align__(16) unsigned short Ps[4][16 * 136]; // per-wave P, padded

    const int tid = threadIdx.x;
    const int w = tid >> 6, l = tid & 63;
    const int lr = l >> 4, lc = l & 15;

    // XCD swizzle: blocks sharing a head's K/V land contiguously on one XCD
    int f = blockIdx.x + blockIdx.y * gridDim.x;
    f = (f & 7) * ((gridDim.x * gridDim.y) >> 3) + (f >> 3);
    const int q0 = (f % gridDim.x) * 64;
    const int bh = f / gridDim.x;
    const int b = bh / HEADS, h = bh % HEADS;

    short8 aq[2];
#pragma unroll
    for (int kk = 0; kk < 2; kk++) {
        const int tok = b * SEQ + q0 + w * 16 + lc;
        aq[kk] = *(const short8*)&qkv[(size_t)tok * QKVN + h * HDIM + kk * 32 + 8 * lr];
    }

    const float C1 = 0.18033688011112042f;   // 0.125 * log2(e): S*C1 = log2-domain logits
    f32x4 oacc[4] = {};
    float mstc[4], lst[4];
#pragma unroll
    for (int r = 0; r < 4; r++) { mstc[r] = -1e30f; lst[r] = 0.0f; }

    for (int kv0 = 0; kv0 < SEQ; kv0 += 128) {
        __syncthreads();
#pragma unroll
        for (int c = 0; c < 4; c++) {
            const int o = c * 4096 + tid * 16;
            const int krow = o >> 7, pc = o & 127;
            const int lcb = pc ^ ((krow & 7) << 4);
            load16(&qkv[(size_t)(b * SEQ + kv0 + krow) * QKVN + EMBED + h * HDIM + (lcb >> 1)],
                   (char*)Ks + o);
        }
#pragma unroll
        for (int c = 0; c < 4; c++) {
            const int o = c * 4096 + tid * 16;
            const int drow = o >> 8, pc = o & 255;
            const int lcb = pc ^ ((drow & 7) << 4);
            load16(&vt[(size_t)(bh * HDIM + drow) * SEQ + kv0 + (lcb >> 1)], (char*)Vs + o);
        }
        __syncthreads();

        // S = Q K^T   (16 q-rows x 128 kv)
        f32x4 s[8] = {};
#pragma unroll
        for (int kk = 0; kk < 2; kk++) {
            short8 bk[8];
#pragma unroll
            for (int nj = 0; nj < 8; nj++) {
                const int krow = nj * 16 + lc;
                const int kb = kk * 64 + lr * 16;
                bk[nj] = *(const short8*)((const char*)Ks + krow * 128 + (kb ^ ((krow & 7) << 4)));
            }
#pragma unroll
            for (int nj = 0; nj < 8; nj++)
                s[nj] = __builtin_amdgcn_mfma_f32_16x16x32_bf16(aq[kk], bk[nj], s[nj], 0, 0, 0);
        }

        // online softmax in exp2-scaled units (scale folded into C1)
#pragma unroll
        for (int r = 0; r < 4; r++) {
            float mt = s[0][r];
#pragma unroll
            for (int nj = 1; nj < 8; nj++) mt = fmaxf(mt, s[nj][r]);
#pragma unroll
            for (int m = 1; m < 16; m <<= 1) mt = fmaxf(mt, __shfl_xor(mt, m));
            const float mnc = fmaxf(mstc[r], mt * C1);
            const float c_ = exp2f(mstc[r] - mnc);
            mstc[r] = mnc;
            float rsum = 0.0f;
#pragma unroll
            for (int nj = 0; nj < 8; nj++) {
                const float pv = exp2f(__builtin_fmaf(s[nj][r], C1, -mnc));
                s[nj][r] = pv;
                rsum += pv;
            }
#pragma unroll
            for (int m = 1; m < 16; m <<= 1) rsum += __shfl_xor(rsum, m);
            lst[r] = lst[r] * c_ + rsum;
#pragma unroll
            for (int dj = 0; dj < 4; dj++) oacc[dj][r] *= c_;
        }

        // P -> per-wave LDS (row-major [q][kv], padded stride 136); truncating bf16 (P in [0,1])
#pragma unroll
        for (int nj = 0; nj < 8; nj++)
#pragma unroll
            for (int r = 0; r < 4; r++)
                Ps[w][(4 * lr + r) * 136 + nj * 16 + lc] =
                    (unsigned short)(__builtin_bit_cast(uint32_t, s[nj][r]) >> 16);

        // O += P V
#pragma unroll
        for (int kk = 0; kk < 4; kk++) {
            short8 pa, bv[4];
            pa = *(const short8*)&Ps[w][lc * 136 + kk * 32 + 8 * lr];
#pragma unroll
            for (int dj = 0; dj < 4; dj++) {
                const int drow = dj * 16 + lc;
                const int kb = kk * 64 + lr * 16;
                bv[dj] = *(const short8*)((const char*)Vs + drow * 256 + (kb ^ ((drow & 7) << 4)));
            }
#pragma unroll
            for (int dj = 0; dj < 4; dj++)
                oacc[dj] = __builtin_amdgcn_mfma_f32_16x16x32_bf16(pa, bv[dj], oacc[dj], 0, 0, 0);
        }
    }

#pragma unroll
    for (int dj = 0; dj < 4; dj++)
#pragma unroll
        for (int r = 0; r < 4; r++) {
            const int q = q0 + w * 16 + 4 * lr + r;
            const int col = h * HDIM + dj * 16 + lc;
            o_out[(size_t)(b * SEQ + q) * EMBED + col] = f2bf(oacc[dj][r] / lst[r]);
        }
}

extern "C" void kernel_launch(void* const* d_in, const int* in_sizes, int n_in,
                              void* d_out, int out_size, void* d_ws, size_t ws_size,
                              hipStream_t stream) {
    const float* x      = (const float*)d_in[0];
    const float* ln1_g  = (const float*)d_in[1];
    const float* ln1_b  = (const float*)d_in[2];
    const float* qkv_w  = (const float*)d_in[3];
    const float* qkv_b  = (const float*)d_in[4];
    const float* proj_w = (const float*)d_in[5];
    const float* proj_b = (const float*)d_in[6];
    const float* ln2_g  = (const float*)d_in[7];
    const float* ln2_b  = (const float*)d_in[8];
    const float* fc1_w  = (const float*)d_in[9];
    const float* fc1_b  = (const float*)d_in[10];
    const float* fc2_w  = (const float*)d_in[11];
    const float* fc2_b  = (const float*)d_in[12];

    char* ws = (char*)d_ws;
    unsigned short* hbuf = (unsigned short*)(ws + 0);         // 6.29 MB: h -> o -> h2
    unsigned short* qkv  = (unsigned short*)(ws + 6291456);   // 18.87 MB
    unsigned short* vt   = (unsigned short*)(ws + 25165824);  // 6.29 MB
    float*          x2   = (float*)(ws + 31457280);           // 12.58 MB
    unsigned short* gbuf = (unsigned short*)(ws + 6291456);   // aliases qkv+vt (both dead)
    unsigned short* wq   = (unsigned short*)(ws + 44040192);  // 3.54 MB
    unsigned short* wp   = (unsigned short*)(ws + 47579136);  // 1.18 MB
    unsigned short* w1   = (unsigned short*)(ws + 48758784);  // 4.72 MB
    unsigned short* w2   = (unsigned short*)(ws + 53477376);  // 4.72 MB

    cvt4_k<<<dim3(2048), 256, 0, stream>>>(qkv_w, wq, QKVN * EMBED / 4,
                                           proj_w, wp, EMBED * EMBED / 4,
                                           fc1_w, w1, HIDDEN * EMBED / 4,
                                           fc2_w, w2, EMBED * HIDDEN / 4);

    ln_k<<<dim3(NTOK), 256, 0, stream>>>(x, ln1_g, ln1_b, hbuf);

    gemm_bt<0, 256, 256, 2, 4><<<dim3((NTOK / 256) * (QKVN / 256)), 512, 0, stream>>>(
        hbuf, wq, qkv_b, nullptr, qkv, vt, NTOK, QKVN, EMBED);

    attn_k<<<dim3(SEQ / 64, BSZ * HEADS), 256, 0, stream>>>(qkv, vt, hbuf);

    gemm_bt<1, 128, 128, 2, 2><<<dim3((NTOK / 128) * (EMBED / 128)), 256, 0, stream>>>(
        hbuf, wp, proj_b, x, x2, nullptr, NTOK, EMBED, EMBED);

    ln_k<<<dim3(NTOK), 256, 0, stream>>>(x2, ln2_g, ln2_b, hbuf);

    gemm_bt<2, 256, 256, 2, 4><<<dim3((NTOK / 256) * (HIDDEN / 256)), 512, 0, stream>>>(
        hbuf, w1, fc1_b, nullptr, gbuf, nullptr, NTOK, HIDDEN, EMBED);

    gemm_bt<3, 128, 128, 2, 2><<<dim3((NTOK / 128) * (EMBED / 128)), 256, 0, stream>>>(
        gbuf, w2, fc2_b, x2, d_out, nullptr, NTOK, EMBED, HIDDEN);
}

// Round 7
// 294.992 us; speedup vs baseline: 1.2684x; 1.2684x over previous
//
#include <hip/hip_runtime.h>
#include <stdint.h>

#define EMBED  768
#define HEADS  12
#define HDIM   64
#define HIDDEN 3072
#define BSZ    2
#define SEQ    2048
#define NTOK   4096
#define QKVN   2304

typedef short short8 __attribute__((ext_vector_type(8)));
typedef float f32x4 __attribute__((ext_vector_type(4)));
typedef float float4v __attribute__((ext_vector_type(4)));
typedef unsigned short ushort4v __attribute__((ext_vector_type(4)));

__device__ __forceinline__ unsigned short f2bf(float f) {
    uint32_t x = __builtin_bit_cast(uint32_t, f);
    x = x + 0x7fffu + ((x >> 16) & 1u);   // RNE
    return (unsigned short)(x >> 16);
}
__device__ __forceinline__ void load16(const void* g, void* l) {
    __builtin_amdgcn_global_load_lds((const __attribute__((address_space(1))) void*)g,
                                     (__attribute__((address_space(3))) void*)l, 16, 0, 0);
}

// ---------------- fp32 -> bf16 convert, all 4 weights in one launch ----------------
__global__ __launch_bounds__(256) void cvt4_k(const float* __restrict__ s0, unsigned short* __restrict__ o0, int n0,
                                              const float* __restrict__ s1, unsigned short* __restrict__ o1, int n1,
                                              const float* __restrict__ s2, unsigned short* __restrict__ o2, int n2,
                                              const float* __restrict__ s3, unsigned short* __restrict__ o3, int n3) {
    int i = blockIdx.x * blockDim.x + threadIdx.x;
    const int stride = gridDim.x * blockDim.x;
    const int tot = n0 + n1 + n2 + n3;   // float4 units
    for (; i < tot; i += stride) {
        const float* s; unsigned short* o; int j = i;
        if (j < n0) { s = s0; o = o0; }
        else if ((j -= n0) < n1) { s = s1; o = o1; }
        else if ((j -= n1) < n2) { s = s2; o = o2; }
        else { j -= n2; s = s3; o = o3; }
        float4v v = ((const float4v*)s)[j];
        ushort4v u;
#pragma unroll
        for (int t = 0; t < 4; t++) u[t] = f2bf(v[t]);
        ((ushort4v*)o)[j] = u;
    }
}

// ---------------- LayerNorm (fp32 in, bf16 out) ----------------
__global__ __launch_bounds__(256) void ln_k(const float* __restrict__ x,
                                            const float* __restrict__ g,
                                            const float* __restrict__ b,
                                            unsigned short* __restrict__ out) {
    const int row = blockIdx.x;
    const int t = threadIdx.x;
    const float* xr = x + (size_t)row * EMBED;
    float v0 = xr[t], v1 = xr[t + 256], v2 = xr[t + 512];
    float s = v0 + v1 + v2;
    float s2 = v0 * v0 + v1 * v1 + v2 * v2;
#pragma unroll
    for (int m = 1; m < 64; m <<= 1) { s += __shfl_xor(s, m); s2 += __shfl_xor(s2, m); }
    __shared__ float red[8];
    const int w = t >> 6;
    if ((t & 63) == 0) { red[w] = s; red[4 + w] = s2; }
    __syncthreads();
    s = red[0] + red[1] + red[2] + red[3];
    s2 = red[4] + red[5] + red[6] + red[7];
    const float mu = s * (1.0f / EMBED);
    const float var = s2 * (1.0f / EMBED) - mu * mu;
    const float rs = rsqrtf(var + 1e-5f);
    unsigned short* orow = out + (size_t)row * EMBED;
    orow[t]       = f2bf((v0 - mu) * rs * g[t]       + b[t]);
    orow[t + 256] = f2bf((v1 - mu) * rs * g[t + 256] + b[t + 256]);
    orow[t + 512] = f2bf((v2 - mu) * rs * g[t + 512] + b[t + 512]);
}

// ---------------- GEMM: C[M,N] = A[M,K](bf16) * W[N,K]^T(bf16) + bias ----------------
// 2-phase double-buffered staging (stage-issue -> ds_read -> MFMA, one barrier per
// 32-K step = T3-minimum recipe), XCD-swizzled block ids, involution bank-swizzle
// on LDS tiles (read 8-way conflict -> 2-way/free; staging source pre-swizzled,
// rule #21), through-LDS coalesced epilogue for bf16 outputs.
// EPI: 0 = QKV (bf16 out + transposed-V side write), 1 = proj (+res, fp32 out),
//      2 = FC1 (GELU, bf16 out), 3 = FC2 (+res, fp32 out)
template <int EPI, int BM, int BN, int WM, int WN>
__global__ __launch_bounds__(256)
void gemm_bt(const unsigned short* __restrict__ A,
             const unsigned short* __restrict__ W,
             const float* __restrict__ bias,
             const float* __restrict__ res,
             void* __restrict__ outp,
             unsigned short* __restrict__ vt,
             int M, int N, int K) {
    constexpr int MI = BM / (WM * 16);
    constexpr int NJ = BN / (WN * 16);
    constexpr int BUFB = (BM + BN) * 64;   // bytes per 32-K tile (A+B)
    constexpr int SMEMB = (EPI == 0 || EPI == 2)
                              ? (2 * BUFB > 36864 ? 2 * BUFB : 36864)
                              : 2 * BUFB;
    __shared__ __align__(16) char smem[SMEMB];

    const int tid = threadIdx.x;
    const int w = tid >> 6, l = tid & 63;
    const int lr = l >> 4, lc = l & 15;
    const int nb = N / BN;

    // bijective XCD swizzle (gridDim.x % 8 == 0 for all our grids)
    int bid = blockIdx.x;
    bid = (bid & 7) * (gridDim.x >> 3) + (bid >> 3);
    const int bx = bid % nb, by = bid / nb;
    const int row0 = by * BM, col0 = bx * BN;
    const int wr = w / WN, wc = w % WN;
    const int srow = tid >> 2;
    const int sksw = ((tid & 3) * 8) ^ (((srow >> 1) & 3) << 3);  // pre-swizzled K-col (shorts)
    const int asw = 8 * (lr ^ ((lc >> 1) & 3));                   // read-side swizzled K-off

    f32x4 acc[MI][NJ] = {};

    const unsigned short* Ag0 = A + (size_t)(row0 + srow) * K + sksw;
    const unsigned short* Ag1 = A + (size_t)(row0 + 64 + srow) * K + sksw;
    const unsigned short* Wg0 = W + (size_t)(col0 + srow) * K + sksw;
    const unsigned short* Wg1 = W + (size_t)(col0 + 64 + srow) * K + sksw;

    auto stage = [&](int buf, int k0) {
        char* base = smem + buf * BUFB;
        load16(Ag0 + k0, base + tid * 16);
        if (BM > 64) load16(Ag1 + k0, base + 4096 + tid * 16);
        char* bb = base + BM * 64;
        load16(Wg0 + k0, bb + tid * 16);
        if (BN >= 128) load16(Wg1 + k0, bb + 4096 + tid * 16);
        else if (BN > 64) { if (tid < (BN - 64) * 4) load16(Wg1 + k0, bb + 4096 + tid * 16); }
    };
    auto compute = [&](int buf) {
        const unsigned short* Asb = (const unsigned short*)(smem + buf * BUFB);
        const unsigned short* Bsb = Asb + BM * 32;
        short8 bfr[NJ];
#pragma unroll
        for (int j = 0; j < NJ; j++)
            bfr[j] = *(const short8*)&Bsb[(wc * NJ * 16 + j * 16 + lc) * 32 + asw];
#pragma unroll
        for (int i = 0; i < MI; i++) {
            short8 af = *(const short8*)&Asb[(wr * MI * 16 + i * 16 + lc) * 32 + asw];
#pragma unroll
            for (int j = 0; j < NJ; j++)
                acc[i][j] = __builtin_amdgcn_mfma_f32_16x16x32_bf16(af, bfr[j], acc[i][j], 0, 0, 0);
        }
    };

    stage(0, 0);
    for (int k0 = 0; k0 < K; k0 += 64) {           // K % 64 == 0 for all 4 GEMMs
        __syncthreads();                            // drains prior loads (vmcnt 0)
        stage(1, k0 + 32);
        compute(0);
        __syncthreads();
        if (k0 + 64 < K) stage(0, k0 + 64);
        compute(1);
    }

    if (EPI == 0 || EPI == 2) {
        // ---- through-LDS coalesced bf16 epilogue (MI==4 path) ----
        __syncthreads();                       // stage bufs dead; reuse LDS
        unsigned short* ebuf = (unsigned short*)(smem + w * 9216);  // 64x72 shorts, wave-private
        unsigned short* qo = (unsigned short*)outp;
#pragma unroll
        for (int i = 0; i < MI; i++)
#pragma unroll
            for (int j = 0; j < NJ; j++) {
                const int col = col0 + wc * NJ * 16 + j * 16 + lc;
                const float bv = bias[col];
                float v[4];
#pragma unroll
                for (int r = 0; r < 4; r++) {
                    v[r] = acc[i][j][r] + bv;
                    if (EPI == 2) v[r] = 0.5f * v[r] * (1.0f + erff(v[r] * 0.70710678118f));
                }
                if (EPI == 0 && col >= 2 * EMBED) {   // V -> [bh][d][n]
                    const int r0 = row0 + wr * MI * 16 + i * 16 + 4 * lr;
                    const int hh = (col - 2 * EMBED) >> 6, d = col & 63;
                    const int bb = r0 >> 11, n0 = r0 & (SEQ - 1);
                    ushort4v pk;
#pragma unroll
                    for (int r = 0; r < 4; r++) pk[r] = f2bf(v[r]);
                    *(ushort4v*)&vt[((size_t)(bb * HEADS + hh) * HDIM + d) * SEQ + n0] = pk;
                }
#pragma unroll
                for (int r = 0; r < 4; r++)
                    ebuf[(i * 16 + 4 * lr + r) * 72 + j * 16 + lc] = f2bf(v[r]);
            }
        const int grow = row0 + wr * MI * 16, gcol = col0 + wc * NJ * 16;
        const int rl0 = l >> 3, c8 = (l & 7) * 8;
#pragma unroll
        for (int k = 0; k < 8; k++) {
            const int rl = k * 8 + rl0;
            short8 vv = *(const short8*)&ebuf[rl * 72 + c8];
            *(short8*)&qo[(size_t)(grow + rl) * N + gcol + c8] = vv;
        }
    } else {
        float* fo = (float*)outp;
#pragma unroll
        for (int i = 0; i < MI; i++) {
            const int r0 = row0 + wr * MI * 16 + i * 16 + 4 * lr;
#pragma unroll
            for (int j = 0; j < NJ; j++) {
                const int col = col0 + wc * NJ * 16 + j * 16 + lc;
                const float bv = bias[col];
#pragma unroll
                for (int r = 0; r < 4; r++)
                    fo[(size_t)(r0 + r) * N + col] =
                        acc[i][j][r] + bv + res[(size_t)(r0 + r) * N + col];
            }
        }
    }
}

// ---------------- Flash attention ----------------
// grid (SEQ/64, BSZ*HEADS), 256 thr. Q tile 64 rows (16/wave), KV tiles 128.
__global__ __launch_bounds__(256) void attn_k(const unsigned short* __restrict__ qkv,
                                              const unsigned short* __restrict__ vt,
                                              unsigned short* __restrict__ o_out) {
    __shared__ __align__(16) unsigned short Ks[128 * 64];    // [kv][d]  XOR-swizzled
    __shared__ __align__(16) unsigned short Vs[64 * 128];    // [d][kv]  XOR-swizzled
    __shared__ __align__(16) unsigned short Ps[4][16 * 136]; // per-wave P, padded

    const int tid = threadIdx.x;
    const int w = tid >> 6, l = tid & 63;
    const int lr = l >> 4, lc = l & 15;

    // XCD swizzle: blocks sharing a head's K/V land contiguously on one XCD
    int f = blockIdx.x + blockIdx.y * gridDim.x;
    f = (f & 7) * ((gridDim.x * gridDim.y) >> 3) + (f >> 3);
    const int q0 = (f % gridDim.x) * 64;
    const int bh = f / gridDim.x;
    const int b = bh / HEADS, h = bh % HEADS;

    short8 aq[2];
#pragma unroll
    for (int kk = 0; kk < 2; kk++) {
        const int tok = b * SEQ + q0 + w * 16 + lc;
        aq[kk] = *(const short8*)&qkv[(size_t)tok * QKVN + h * HDIM + kk * 32 + 8 * lr];
    }

    const float C1 = 0.18033688011112042f;   // 0.125 * log2(e)
    f32x4 oacc[4] = {};
    float mstc[4], lst[4];
#pragma unroll
    for (int r = 0; r < 4; r++) { mstc[r] = -1e30f; lst[r] = 0.0f; }

    for (int kv0 = 0; kv0 < SEQ; kv0 += 128) {
        __syncthreads();
#pragma unroll
        for (int c = 0; c < 4; c++) {
            const int o = c * 4096 + tid * 16;
            const int krow = o >> 7, pc = o & 127;
            const int lcb = pc ^ ((krow & 7) << 4);
            load16(&qkv[(size_t)(b * SEQ + kv0 + krow) * QKVN + EMBED + h * HDIM + (lcb >> 1)],
                   (char*)Ks + o);
        }
#pragma unroll
        for (int c = 0; c < 4; c++) {
            const int o = c * 4096 + tid * 16;
            const int drow = o >> 8, pc = o & 255;
            const int lcb = pc ^ ((drow & 7) << 4);
            load16(&vt[(size_t)(bh * HDIM + drow) * SEQ + kv0 + (lcb >> 1)], (char*)Vs + o);
        }
        __syncthreads();

        // S = Q K^T   (16 q-rows x 128 kv)
        f32x4 s[8] = {};
#pragma unroll
        for (int kk = 0; kk < 2; kk++) {
            short8 bk[8];
#pragma unroll
            for (int nj = 0; nj < 8; nj++) {
                const int krow = nj * 16 + lc;
                const int kb = kk * 64 + lr * 16;
                bk[nj] = *(const short8*)((const char*)Ks + krow * 128 + (kb ^ ((krow & 7) << 4)));
            }
#pragma unroll
            for (int nj = 0; nj < 8; nj++)
                s[nj] = __builtin_amdgcn_mfma_f32_16x16x32_bf16(aq[kk], bk[nj], s[nj], 0, 0, 0);
        }

        // online softmax in log2 units, defer-max (skip rescale when growth <= 3)
        float mt[4];
#pragma unroll
        for (int r = 0; r < 4; r++) {
            float m_ = s[0][r];
#pragma unroll
            for (int nj = 1; nj < 8; nj++) m_ = fmaxf(m_, s[nj][r]);
#pragma unroll
            for (int m = 1; m < 16; m <<= 1) m_ = fmaxf(m_, __shfl_xor(m_, m));
            mt[r] = m_ * C1;
        }
        const float gr = fmaxf(fmaxf(mt[0] - mstc[0], mt[1] - mstc[1]),
                               fmaxf(mt[2] - mstc[2], mt[3] - mstc[3]));
        if (!__all(gr <= 3.0f)) {
#pragma unroll
            for (int r = 0; r < 4; r++) {
                const float mnc = fmaxf(mstc[r], mt[r]);
                const float c_ = exp2f(mstc[r] - mnc);
                mstc[r] = mnc;
                lst[r] *= c_;
#pragma unroll
                for (int dj = 0; dj < 4; dj++) oacc[dj][r] *= c_;
            }
        }
#pragma unroll
        for (int r = 0; r < 4; r++) {
            float rsum = 0.0f;
#pragma unroll
            for (int nj = 0; nj < 8; nj++) {
                const float pv = exp2f(__builtin_fmaf(s[nj][r], C1, -mstc[r]));
                s[nj][r] = pv;
                rsum += pv;
            }
#pragma unroll
            for (int m = 1; m < 16; m <<= 1) rsum += __shfl_xor(rsum, m);
            lst[r] += rsum;
        }

        // P -> per-wave LDS (row-major [q][kv], padded stride 136); truncating bf16 (P in [0,8))
#pragma unroll
        for (int nj = 0; nj < 8; nj++)
#pragma unroll
            for (int r = 0; r < 4; r++)
                Ps[w][(4 * lr + r) * 136 + nj * 16 + lc] =
                    (unsigned short)(__builtin_bit_cast(uint32_t, s[nj][r]) >> 16);

        // O += P V
#pragma unroll
        for (int kk = 0; kk < 4; kk++) {
            short8 pa, bv[4];
            pa = *(const short8*)&Ps[w][lc * 136 + kk * 32 + 8 * lr];
#pragma unroll
            for (int dj = 0; dj < 4; dj++) {
                const int drow = dj * 16 + lc;
                const int kb = kk * 64 + lr * 16;
                bv[dj] = *(const short8*)((const char*)Vs + drow * 256 + (kb ^ ((drow & 7) << 4)));
            }
#pragma unroll
            for (int dj = 0; dj < 4; dj++)
                oacc[dj] = __builtin_amdgcn_mfma_f32_16x16x32_bf16(pa, bv[dj], oacc[dj], 0, 0, 0);
        }
    }

#pragma unroll
    for (int dj = 0; dj < 4; dj++)
#pragma unroll
        for (int r = 0; r < 4; r++) {
            const int q = q0 + w * 16 + 4 * lr + r;
            const int col = h * HDIM + dj * 16 + lc;
            o_out[(size_t)(b * SEQ + q) * EMBED + col] = f2bf(oacc[dj][r] / lst[r]);
        }
}

extern "C" void kernel_launch(void* const* d_in, const int* in_sizes, int n_in,
                              void* d_out, int out_size, void* d_ws, size_t ws_size,
                              hipStream_t stream) {
    const float* x      = (const float*)d_in[0];
    const float* ln1_g  = (const float*)d_in[1];
    const float* ln1_b  = (const float*)d_in[2];
    const float* qkv_w  = (const float*)d_in[3];
    const float* qkv_b  = (const float*)d_in[4];
    const float* proj_w = (const float*)d_in[5];
    const float* proj_b = (const float*)d_in[6];
    const float* ln2_g  = (const float*)d_in[7];
    const float* ln2_b  = (const float*)d_in[8];
    const float* fc1_w  = (const float*)d_in[9];
    const float* fc1_b  = (const float*)d_in[10];
    const float* fc2_w  = (const float*)d_in[11];
    const float* fc2_b  = (const float*)d_in[12];

    char* ws = (char*)d_ws;
    unsigned short* hbuf = (unsigned short*)(ws + 0);         // 6.29 MB: h -> o -> h2
    unsigned short* qkv  = (unsigned short*)(ws + 6291456);   // 18.87 MB
    unsigned short* vt   = (unsigned short*)(ws + 25165824);  // 6.29 MB
    float*          x2   = (float*)(ws + 31457280);           // 12.58 MB
    unsigned short* gbuf = (unsigned short*)(ws + 6291456);   // aliases qkv+vt (both dead)
    unsigned short* wq   = (unsigned short*)(ws + 44040192);  // 3.54 MB
    unsigned short* wp   = (unsigned short*)(ws + 47579136);  // 1.18 MB
    unsigned short* w1   = (unsigned short*)(ws + 48758784);  // 4.72 MB
    unsigned short* w2   = (unsigned short*)(ws + 53477376);  // 4.72 MB

    cvt4_k<<<dim3(2048), 256, 0, stream>>>(qkv_w, wq, QKVN * EMBED / 4,
                                           proj_w, wp, EMBED * EMBED / 4,
                                           fc1_w, w1, HIDDEN * EMBED / 4,
                                           fc2_w, w2, EMBED * HIDDEN / 4);

    ln_k<<<dim3(NTOK), 256, 0, stream>>>(x, ln1_g, ln1_b, hbuf);

    gemm_bt<0, 128, 128, 2, 2><<<dim3((NTOK / 128) * (QKVN / 128)), 256, 0, stream>>>(
        hbuf, wq, qkv_b, nullptr, qkv, vt, NTOK, QKVN, EMBED);

    attn_k<<<dim3(SEQ / 64, BSZ * HEADS), 256, 0, stream>>>(qkv, vt, hbuf);

    gemm_bt<1, 64, 96, 2, 2><<<dim3((NTOK / 64) * (EMBED / 96)), 256, 0, stream>>>(
        hbuf, wp, proj_b, x, x2, nullptr, NTOK, EMBED, EMBED);

    ln_k<<<dim3(NTOK), 256, 0, stream>>>(x2, ln2_g, ln2_b, hbuf);

    gemm_bt<2, 128, 128, 2, 2><<<dim3((NTOK / 128) * (HIDDEN / 128)), 256, 0, stream>>>(
        hbuf, w1, fc1_b, nullptr, gbuf, nullptr, NTOK, HIDDEN, EMBED);

    gemm_bt<3, 64, 96, 2, 2><<<dim3((NTOK / 64) * (EMBED / 96)), 256, 0, stream>>>(
        gbuf, w2, fc2_b, x2, d_out, nullptr, NTOK, EMBED, HIDDEN);
}